// Round 1
// baseline (6640.368 us; speedup 1.0000x reference)
//
#include <hip/hip_runtime.h>
#include <cstdint>

#define GG   29
#define GG2  841
#define GG3  24389
#define DD   15
#define DD3  3375
#define SS   48
#define CC   16
#define NVOX (SS*SS*SS)        // 110592
#define FT_ELEMS (NVOX*CC)     // 1769472

__device__ __forceinline__ int clampi(int v, int lo, int hi) {
    return min(max(v, lo), hi);
}

// ---------------- transpose [C,S,S,S] -> [S*S*S, C] ----------------
__global__ void __launch_bounds__(256) k_transpose(const float* __restrict__ f,
                                                   float* __restrict__ ft) {
    int idx = blockIdx.x * 256 + threadIdx.x;
    if (idx < FT_ELEMS) {
        int c = idx & 15;
        int v = idx >> 4;
        ft[idx] = f[c * NVOX + v];
    }
}

// ---------------- K1: deeds cost volume ----------------
// block = one grid point g; threads stride over D^3 displacements.
__global__ void __launch_bounds__(256) k_cost(const float* __restrict__ f5t,
                                              const float* __restrict__ f0t,
                                              const float* __restrict__ alpha,
                                              float* __restrict__ dc) {
    __shared__ int   i0s[3][DD];
    __shared__ float wss[3][DD];
    __shared__ float4 fixv4[4];
    int tid = threadIdx.x;
    int g = blockIdx.x;
    int gx = g % GG; int gy = (g / GG) % GG; int gz = g / GG2;

    if (tid < 3 * DD) {
        int axis = tid / DD, j = tid % DD;
        int gi = (axis == 0) ? gx : (axis == 1) ? gy : gz;
        float cgv = (2.0f * gi + 1.0f) / 29.0f - 1.0f;
        float sj  = 0.4f * ((2.0f * j + 1.0f) / 15.0f - 1.0f);
        float p = ((cgv + sj + 1.0f) * 48.0f - 1.0f) * 0.5f;
        p = fminf(fmaxf(p, 0.0f), 47.0f);
        float fl = floorf(p);
        i0s[axis][j] = (int)fl;
        wss[axis][j] = p - fl;
    }
    if (tid < CC) {
        // fixed-image feature at the (unshifted) grid point, channel = tid
        int giv[3] = {gx, gy, gz};
        int i0[3]; float w[3];
        #pragma unroll
        for (int a = 0; a < 3; ++a) {
            float cgv = (2.0f * giv[a] + 1.0f) / 29.0f - 1.0f;
            float p = ((cgv + 1.0f) * 48.0f - 1.0f) * 0.5f;
            p = fminf(fmaxf(p, 0.0f), 47.0f);
            float fl = floorf(p);
            i0[a] = (int)fl; w[a] = p - fl;
        }
        int x0 = i0[0], y0 = i0[1], z0 = i0[2];
        int x1 = min(x0 + 1, 47), y1 = min(y0 + 1, 47), z1 = min(z0 + 1, 47);
        float wx = w[0], wy = w[1], wz = w[2];
        float ux = 1.0f - wx, uy = 1.0f - wy, uz = 1.0f - wz;
        int zy00 = (z0 * SS + y0) * SS, zy01 = (z0 * SS + y1) * SS;
        int zy10 = (z1 * SS + y0) * SS, zy11 = (z1 * SS + y1) * SS;
        float v = uz*uy*ux * f0t[(zy00 + x0) * CC + tid]
                + uz*uy*wx * f0t[(zy00 + x1) * CC + tid]
                + uz*wy*ux * f0t[(zy01 + x0) * CC + tid]
                + uz*wy*wx * f0t[(zy01 + x1) * CC + tid]
                + wz*uy*ux * f0t[(zy10 + x0) * CC + tid]
                + wz*uy*wx * f0t[(zy10 + x1) * CC + tid]
                + wz*wy*ux * f0t[(zy11 + x0) * CC + tid]
                + wz*wy*wx * f0t[(zy11 + x1) * CC + tid];
        ((float*)fixv4)[tid] = v;
    }
    __syncthreads();

    float a0 = alpha[0], a1 = alpha[1];
    const float4* F4 = (const float4*)f5t;
    float* dcrow = dc + (size_t)g * DD3;

    for (int d = tid; d < DD3; d += 256) {
        int jx = d % DD; int r = d / DD; int jy = r % DD; int jz = r / DD;
        int x0 = i0s[0][jx]; float wx = wss[0][jx];
        int y0 = i0s[1][jy]; float wy = wss[1][jy];
        int z0 = i0s[2][jz]; float wz = wss[2][jz];
        int x1 = min(x0 + 1, 47), y1 = min(y0 + 1, 47), z1 = min(z0 + 1, 47);
        float ux = 1.0f - wx, uy = 1.0f - wy, uz = 1.0f - wz;
        float w000 = uz*uy*ux, w001 = uz*uy*wx, w010 = uz*wy*ux, w011 = uz*wy*wx;
        float w100 = wz*uy*ux, w101 = wz*uy*wx, w110 = wz*wy*ux, w111 = wz*wy*wx;
        int zy00 = (z0*SS+y0)*SS, zy01 = (z0*SS+y1)*SS;
        int zy10 = (z1*SS+y0)*SS, zy11 = (z1*SS+y1)*SS;
        int v000 = (zy00+x0)*4, v001 = (zy00+x1)*4, v010 = (zy01+x0)*4, v011 = (zy01+x1)*4;
        int v100 = (zy10+x0)*4, v101 = (zy10+x1)*4, v110 = (zy11+x0)*4, v111 = (zy11+x1)*4;
        float acc = 0.0f;
        #pragma unroll
        for (int q = 0; q < 4; ++q) {
            float4 c000 = F4[v000+q], c001 = F4[v001+q], c010 = F4[v010+q], c011 = F4[v011+q];
            float4 c100 = F4[v100+q], c101 = F4[v101+q], c110 = F4[v110+q], c111 = F4[v111+q];
            float4 fx = fixv4[q];
            float mv, dv;
            mv = w000*c000.x + w001*c001.x + w010*c010.x + w011*c011.x
               + w100*c100.x + w101*c101.x + w110*c110.x + w111*c111.x;
            dv = fx.x - mv; acc += dv*dv;
            mv = w000*c000.y + w001*c001.y + w010*c010.y + w011*c011.y
               + w100*c100.y + w101*c101.y + w110*c110.y + w111*c111.y;
            dv = fx.y - mv; acc += dv*dv;
            mv = w000*c000.z + w001*c001.z + w010*c010.z + w011*c011.z
               + w100*c100.z + w101*c101.z + w110*c110.z + w111*c111.z;
            dv = fx.z - mv; acc += dv*dv;
            mv = w000*c000.w + w001*c001.w + w010*c010.w + w011*c011.w
               + w100*c100.w + w101*c101.w + w110*c110.w + w111*c111.w;
            dv = fx.w - mv; acc += dv*dv;
        }
        dcrow[d] = a1 + a0 * acc;
    }
}

// ------------- shared minavg_disp: B[0..3374] holds the input row -------------
// pad_rep(3) -> min3 -> avg3 -> avg3, fully separable. Ping-pong A(8379)/B(7581).
__device__ __forceinline__ void minavg_from_B(float* Abuf, float* Bbuf,
                                              float* outrow, int tid) {
    const float W0 = 1.0f/9.0f, W1 = 2.0f/9.0f, W2 = 3.0f/9.0f;
    __syncthreads();
    // Mz: A[19][21][21], reading B with clamped (replicate-pad) indices
    for (int idx = tid; idx < 19*21*21; idx += 256) {
        int xi = idx % 21; int r = idx / 21; int yi = r % 21; int zi = r / 21;
        int sx = clampi(xi - 3, 0, 14);
        int sy = clampi(yi - 3, 0, 14);
        int z0 = clampi(zi - 3, 0, 14), z1 = clampi(zi - 2, 0, 14), z2 = clampi(zi - 1, 0, 14);
        int o = sy * 15 + sx;
        Abuf[idx] = fminf(fminf(Bbuf[z0*225 + o], Bbuf[z1*225 + o]), Bbuf[z2*225 + o]);
    }
    __syncthreads();
    // My: B[19][19][21]
    for (int idx = tid; idx < 19*19*21; idx += 256) {
        int xi = idx % 21; int r = idx / 21; int yi = r % 19; int zi = r / 19;
        int b = (zi*21 + yi)*21 + xi;
        Bbuf[idx] = fminf(fminf(Abuf[b], Abuf[b+21]), Abuf[b+42]);
    }
    __syncthreads();
    // Mx: A[19][19][19]
    for (int idx = tid; idx < 19*19*19; idx += 256) {
        int xi = idx % 19; int r = idx / 19; int yi = r % 19; int zi = r / 19;
        int b = (zi*19 + yi)*21 + xi;
        Abuf[idx] = fminf(fminf(Bbuf[b], Bbuf[b+1]), Bbuf[b+2]);
    }
    __syncthreads();
    // Cz: B[15][19][19]   (conv [1,2,3,2,1]/9 along z)
    for (int idx = tid; idx < 15*19*19; idx += 256) {
        int xi = idx % 19; int r = idx / 19; int yi = r % 19; int zi = r / 19;
        int b = (zi*19 + yi)*19 + xi;
        Bbuf[idx] = W0*(Abuf[b] + Abuf[b + 4*361]) + W1*(Abuf[b + 361] + Abuf[b + 3*361])
                  + W2*Abuf[b + 2*361];
    }
    __syncthreads();
    // Cy: A[15][15][19]
    for (int idx = tid; idx < 15*15*19; idx += 256) {
        int xi = idx % 19; int r = idx / 19; int yi = r % 15; int zi = r / 15;
        int b = (zi*19 + yi)*19 + xi;
        Abuf[idx] = W0*(Bbuf[b] + Bbuf[b + 4*19]) + W1*(Bbuf[b + 19] + Bbuf[b + 3*19])
                  + W2*Bbuf[b + 2*19];
    }
    __syncthreads();
    // Cx: write 15^3 row to global
    for (int idx = tid; idx < DD3; idx += 256) {
        int xi = idx % 15; int r = idx / 15; int yi = r % 15; int zi = r / 15;
        int b = (zi*15 + yi)*19 + xi;
        outrow[idx] = W0*(Abuf[b] + Abuf[b+4]) + W1*(Abuf[b+1] + Abuf[b+3]) + W2*Abuf[b+2];
    }
}

// ---------------- K2: minavg_disp of dc -> c ----------------
__global__ void __launch_bounds__(256) k_minavg(const float* __restrict__ in, float* out) {
    __shared__ float Abuf[19*21*21];
    __shared__ float Bbuf[19*19*21];
    int tid = threadIdx.x;
    size_t base = (size_t)blockIdx.x * DD3;
    for (int d = tid; d < DD3; d += 256) Bbuf[d] = in[base + d];
    minavg_from_B(Abuf, Bbuf, out + base, tid);
}

// ---------------- grid-axis 1D conv [1,2,3,2,1]/9 with clamp (in-place safe) ----------------
__global__ void __launch_bounds__(256) k_conv_grid(const float* in, float* out, int axis) {
    const float W0 = 1.0f/9.0f, W1 = 2.0f/9.0f, W2 = 3.0f/9.0f;
    int d = blockIdx.x * 256 + threadIdx.x;
    if (d >= DD3) return;
    int line = blockIdx.y;   // 0..840
    size_t base, step;
    if (axis == 0) { base = (size_t)line * GG * DD3; step = DD3; }
    else           { int gz = line / GG, gx = line % GG;
                     base = ((size_t)gz * GG2 + gx) * DD3; step = (size_t)GG * DD3; }
    base += (size_t)d;
    float v[GG];
    #pragma unroll
    for (int i = 0; i < GG; ++i) v[i] = in[base + (size_t)i * step];
    #pragma unroll
    for (int i = 0; i < GG; ++i) {
        int im2 = i-2 < 0 ? 0 : i-2, im1 = i-1 < 0 ? 0 : i-1;
        int ip2 = i+2 > 28 ? 28 : i+2, ip1 = i+1 > 28 ? 28 : i+1;
        out[base + (size_t)i * step] = W0*(v[im2] + v[ip2]) + W1*(v[im1] + v[ip1]) + W2*v[i];
    }
}

// ---------------- K4: z-conv of t2 + combine with dc + minavg_disp -> c3 (row-in-place on dc buffer) ----------------
__global__ void __launch_bounds__(256) k_zcomb_minavg(const float* __restrict__ t2,
                                                      const float* dcin,
                                                      const float* __restrict__ alpha,
                                                      float* c3out) {
    __shared__ float Abuf[19*21*21];
    __shared__ float Bbuf[19*19*21];
    const float W0 = 1.0f/9.0f, W1 = 2.0f/9.0f, W2 = 3.0f/9.0f;
    int tid = threadIdx.x;
    int g = blockIdx.x;
    int gx = g % GG; int gy = (g / GG) % GG; int gz = g / GG2;
    float a2 = alpha[2], a3 = alpha[3], a4 = alpha[4];
    size_t rb0 = ((size_t)((clampi(gz-2,0,28)*GG + gy)*GG + gx)) * DD3;
    size_t rb1 = ((size_t)((clampi(gz-1,0,28)*GG + gy)*GG + gx)) * DD3;
    size_t rb2 = ((size_t)((gz*GG + gy)*GG + gx)) * DD3;
    size_t rb3 = ((size_t)((clampi(gz+1,0,28)*GG + gy)*GG + gx)) * DD3;
    size_t rb4 = ((size_t)((clampi(gz+2,0,28)*GG + gy)*GG + gx)) * DD3;
    const float* drow = dcin + (size_t)g * DD3;
    for (int d = tid; d < DD3; d += 256) {
        float ca = W0*(t2[rb0+d] + t2[rb4+d]) + W1*(t2[rb1+d] + t2[rb3+d]) + W2*t2[rb2+d];
        Bbuf[d] = a4 + a2 * drow[d] + a3 * ca;
    }
    minavg_from_B(Abuf, Bbuf, c3out + (size_t)g * DD3, tid);
}

// ---------------- K7: z-conv of t4 -> softmax -> cost_soft + pred_xyz ----------------
__global__ void __launch_bounds__(256) k_zsoftmax(const float* __restrict__ t4,
                                                  const float* __restrict__ alpha,
                                                  float* __restrict__ cost,
                                                  float* __restrict__ pred) {
    __shared__ float row[DD3];
    __shared__ float4 red4[256];
    const float W0 = 1.0f/9.0f, W1 = 2.0f/9.0f, W2 = 3.0f/9.0f;
    int tid = threadIdx.x;
    int g = blockIdx.x;
    int gx = g % GG; int gy = (g / GG) % GG; int gz = g / GG2;
    float a5 = alpha[5];
    size_t rb0 = ((size_t)((clampi(gz-2,0,28)*GG + gy)*GG + gx)) * DD3;
    size_t rb1 = ((size_t)((clampi(gz-1,0,28)*GG + gy)*GG + gx)) * DD3;
    size_t rb2 = ((size_t)((gz*GG + gy)*GG + gx)) * DD3;
    size_t rb3 = ((size_t)((clampi(gz+1,0,28)*GG + gy)*GG + gx)) * DD3;
    size_t rb4 = ((size_t)((clampi(gz+2,0,28)*GG + gy)*GG + gx)) * DD3;

    float lmax = -3.0e38f;
    for (int d = tid; d < DD3; d += 256) {
        float ca = W0*(t4[rb0+d] + t4[rb4+d]) + W1*(t4[rb1+d] + t4[rb3+d]) + W2*t4[rb2+d];
        float v = -a5 * ca;
        row[d] = v;
        lmax = fmaxf(lmax, v);
    }
    red4[tid].x = lmax;
    __syncthreads();
    for (int s = 128; s > 0; s >>= 1) {
        if (tid < s) red4[tid].x = fmaxf(red4[tid].x, red4[tid + s].x);
        __syncthreads();
    }
    float m = red4[0].x;
    __syncthreads();

    float s0 = 0.f, s1 = 0.f, s2 = 0.f, s3 = 0.f;
    for (int d = tid; d < DD3; d += 256) {
        float p = expf(row[d] - m);
        row[d] = p;
        int jx = d % 15; int r = d / 15; int jy = r % 15; int jz = r / 15;
        s0 += p;
        s1 += p * (0.4f * ((2.0f * jx + 1.0f) / 15.0f - 1.0f));
        s2 += p * (0.4f * ((2.0f * jy + 1.0f) / 15.0f - 1.0f));
        s3 += p * (0.4f * ((2.0f * jz + 1.0f) / 15.0f - 1.0f));
    }
    red4[tid] = make_float4(s0, s1, s2, s3);
    __syncthreads();
    for (int s = 128; s > 0; s >>= 1) {
        if (tid < s) {
            float4 a = red4[tid], b = red4[tid + s];
            red4[tid] = make_float4(a.x + b.x, a.y + b.y, a.z + b.z, a.w + b.w);
        }
        __syncthreads();
    }
    float4 tot = red4[0];
    float inv = 1.0f / tot.x;
    size_t base = (size_t)g * DD3;
    for (int d = tid; d < DD3; d += 256) cost[base + d] = row[d] * inv;
    if (tid == 0) {
        pred[g*3 + 0] = tot.y * inv;
        pred[g*3 + 1] = tot.z * inv;
        pred[g*3 + 2] = tot.w * inv;
    }
}

extern "C" void kernel_launch(void* const* d_in, const int* in_sizes, int n_in,
                              void* d_out, int out_size, void* d_ws, size_t ws_size,
                              hipStream_t stream) {
    const float* feat00 = (const float*)d_in[0];
    const float* feat50 = (const float*)d_in[1];
    const float* alpha  = (const float*)d_in[2];
    float* out = (float*)d_out;
    float* ws  = (float*)d_ws;

    float* ft5  = ws;
    float* ft0  = ws + FT_ELEMS;
    float* S0   = ws + 2 * FT_ELEMS;            // dc -> c3 -> t4 (row-local reuse)
    float* DOUT = out;                           // scratch use of output buffer: c -> t2
    float* pred = out + (size_t)GG3 * DD3;

    size_t need = ((size_t)2 * FT_ELEMS + (size_t)GG3 * DD3) * sizeof(float);
    if (ws_size < need) return;  // fail cleanly if workspace too small

    // transpose features to voxel-major [S^3, C] for float4 channel loads
    k_transpose<<<FT_ELEMS / 256, 256, 0, stream>>>(feat50, ft5);
    k_transpose<<<FT_ELEMS / 256, 256, 0, stream>>>(feat00, ft0);

    // dc
    k_cost<<<GG3, 256, 0, stream>>>(ft5, ft0, alpha, S0);
    // c = minavg_disp(dc)
    k_minavg<<<GG3, 256, 0, stream>>>(S0, DOUT);
    // avg_grid x,y on c (in-place; z-conv folded into next kernel)
    dim3 cgrid((DD3 + 255) / 256, GG2);
    k_conv_grid<<<cgrid, 256, 0, stream>>>(DOUT, DOUT, 0);
    k_conv_grid<<<cgrid, 256, 0, stream>>>(DOUT, DOUT, 1);
    // c3 = minavg_disp(a4 + a2*dc + a3*zconv(t2))   (writes over dc buffer, row-local)
    k_zcomb_minavg<<<GG3, 256, 0, stream>>>(DOUT, S0, alpha, S0);
    // avg_grid x,y on c3 (in-place)
    k_conv_grid<<<cgrid, 256, 0, stream>>>(S0, S0, 0);
    k_conv_grid<<<cgrid, 256, 0, stream>>>(S0, S0, 1);
    // z-conv + softmax + pred
    k_zsoftmax<<<GG3, 256, 0, stream>>>(S0, alpha, out, pred);
}